// Round 6
// baseline (237.216 us; speedup 1.0000x reference)
//
#include <hip/hip_runtime.h>
#include <hip/hip_bf16.h>
#include <math.h>

// InteractionEncoder: B=32, N=64, D=256, ID=128, IN=516, H=256
// pair@W1 = A[b,i] + C[b,j] + geo(i,j)@W1[512:516]  (A,C precomputed, b1 folded)
// Layer 2 MFMA bf16 hi/lo (3-term): H[64x256] @ W2ext[256x144],
// cols 128-135 = W2@Wt (itypes), 136 = W2@Wc (causal), 137-143 = 0.
// R6: kill the L2 wall — W2 fragments RESIDENT IN REGISTERS per wave,
// block = (b, 4-i group) reuses them 4x; H rebuilt per i in 64KB LDS.

typedef __attribute__((ext_vector_type(8))) short  bfrag8;  // 8 bf16 bits
typedef __attribute__((ext_vector_type(4))) short  spack4;  // 4 bf16 bits
typedef __attribute__((ext_vector_type(4))) float  fvec4;

#define ITY_OFF   16777216u   // 2048*64*128
#define CAU_OFF   17825792u   // + 2048*64*8

static __device__ __forceinline__ short f2bf(float f) {   // RNE f32->bf16 bits
  unsigned u = __float_as_uint(f);
  u = u + 0x7FFF + ((u >> 16) & 1);
  return (short)(u >> 16);
}
static __device__ __forceinline__ float bf2f(short s) {
  return __uint_as_float(((unsigned)(unsigned short)s) << 16);
}

// ---------------------------------------------------------------------------
// P0: Wtx[k][q] = (W2@Wt | W2@Wc) fully parallel; b2e = b2 | b2@Wt | b2@Wc | 0.
__global__ __launch_bounds__(256) void prep_wtx(
    const float* __restrict__ W2,   // [256][128]
    const float* __restrict__ b2,   // [128]
    const float* __restrict__ Wt,   // [128][8]
    const float* __restrict__ Wc,   // [128]
    float* __restrict__ Wtx,        // [256][16] (cols 0..8 used)
    float* __restrict__ b2e)        // [144]
{
  __shared__ float colv[128];
  __shared__ float red[4];
  const int q   = blockIdx.x;       // 0..8
  const int tid = threadIdx.x;      // k
  if (tid < 128) colv[tid] = (q < 8) ? Wt[tid * 8 + q] : Wc[tid];
  __syncthreads();

  float acc = 0.f;
  #pragma unroll 4
  for (int c = 0; c < 128; ++c)
    acc = fmaf(W2[tid * 128 + c], colv[c], acc);
  Wtx[tid * 16 + q] = acc;

  float p = (tid < 128) ? b2[tid] * colv[tid] : 0.f;
  #pragma unroll
  for (int m = 1; m < 64; m <<= 1) p += __shfl_xor(p, m, 64);
  if ((tid & 63) == 0) red[tid >> 6] = p;
  __syncthreads();
  if (tid == 0) b2e[128 + q] = red[0] + red[1] + red[2] + red[3];
  if (q == 0) {
    if (tid < 128) b2e[tid] = b2[tid];
    if (tid >= 137 && tid < 144) b2e[tid] = 0.f;
  }
}

// ---------------------------------------------------------------------------
// P1: pack W2ext as hi/lo bf16 B-fragments (16x16x32 layout).
__global__ __launch_bounds__(256) void prep_w(
    const float* __restrict__ W2,   // [256][128]
    const float* __restrict__ Wtx,  // [256][16]
    short* __restrict__ WfHi,       // [72][64][8]
    short* __restrict__ WfLo)
{
  const int tid  = threadIdx.x;
  const int tile = blockIdx.x * 4 + (tid >> 6);
  const int l    = tid & 63;
  const int ks   = tile / 9, db = tile - ks * 9;
  const int d    = db * 16 + (l & 15);
  const int k0   = ks * 32 + ((l >> 4) & 3) * 8;

  float v[8];
  if (d < 128) {
    #pragma unroll
    for (int e = 0; e < 8; ++e) v[e] = W2[(k0 + e) * 128 + d];
  } else if (d < 137) {
    #pragma unroll
    for (int e = 0; e < 8; ++e) v[e] = Wtx[(k0 + e) * 16 + (d - 128)];
  } else {
    #pragma unroll
    for (int e = 0; e < 8; ++e) v[e] = 0.f;
  }

  bfrag8 hi, lo;
  #pragma unroll
  for (int e = 0; e < 8; ++e) {
    const short hb = f2bf(v[e]);
    hi[e] = hb;
    lo[e] = f2bf(v[e] - bf2f(hb));
  }
  *(bfrag8*)&WfHi[(tile * 64 + l) * 8] = hi;
  *(bfrag8*)&WfLo[(tile * 64 + l) * 8] = lo;
}

// ---------------------------------------------------------------------------
// P2: A/C precompute. 512 blocks x 512 thr; 4 rows/block; k split in halves.
__global__ __launch_bounds__(512) void prep_ac(
    const float* __restrict__ slots,  // [2048][256]
    const float* __restrict__ W1,     // [516][256]
    const float* __restrict__ b1,     // [256]
    float* __restrict__ Abuf,         // [2048][256] = slots@W1[0:256] + b1
    float* __restrict__ Cbuf)         // [2048][256] = slots@W1[256:512]
{
  __shared__ __align__(16) float s[4][256];
  __shared__ float pA[4][256], pC[4][256];
  const int tid  = threadIdx.x;
  const int col  = tid & 255;
  const int kh   = tid >> 8;
  const int row0 = blockIdx.x * 4;
  {
    const int r = tid >> 7, o = (tid & 127) * 2;
    *(float2*)&s[r][o] = *(const float2*)&slots[(row0 + r) * 256 + o];
  }
  __syncthreads();

  float aA[4] = {0.f,0.f,0.f,0.f};
  float aC[4] = {0.f,0.f,0.f,0.f};
  const int kbase = kh * 128;
  #pragma unroll 2
  for (int kk = 0; kk < 128; ++kk) {
    const int k = kbase + kk;
    const float wa = W1[k * 256 + col];
    const float wc = W1[(256 + k) * 256 + col];
    #pragma unroll
    for (int r = 0; r < 4; ++r) {
      aA[r] = fmaf(s[r][k], wa, aA[r]);
      aC[r] = fmaf(s[r][k], wc, aC[r]);
    }
  }
  if (kh == 1) {
    #pragma unroll
    for (int r = 0; r < 4; ++r) { pA[r][col] = aA[r]; pC[r][col] = aC[r]; }
  }
  __syncthreads();
  if (kh == 0) {
    const float bv = b1[col];
    #pragma unroll
    for (int r = 0; r < 4; ++r) {
      Abuf[(row0 + r) * 256 + col] = aA[r] + pA[r][col] + bv;
      Cbuf[(row0 + r) * 256 + col] = aC[r] + pC[r][col];
    }
  }
}

// ---------------------------------------------------------------------------
// Main: block = (b, ig): 4 i's x 64 j. W2 frags resident in VGPRs per wave.
// Grid 512 x 256 thr. LDS: Hhi[32K]|Hlo[32K] (FS[64][148] reuses front).
__global__ __launch_bounds__(256, 2) void main_kernel(
    const float* __restrict__ positions, // [2048][4]
    const float* __restrict__ em,        // [2048]
    const float* __restrict__ W1,        // [516][256] (geo rows 512..515)
    const float* __restrict__ Abuf,
    const float* __restrict__ Cbuf,
    const float* __restrict__ b2e,       // [144]
    const short* __restrict__ WfHi,
    const short* __restrict__ WfLo,
    const float* __restrict__ bt,        // [8]
    const float* __restrict__ bc,        // [1]
    float* __restrict__ out)
{
  __shared__ __align__(16) char LDSbuf[65536];
  __shared__ float maskL[64];

  const int tid = threadIdx.x;
  const int l   = tid & 63;
  const int w   = tid >> 6;
  // bijective XCD swizzle over 512 blocks (512 % 8 == 0)
  const int wid = (blockIdx.x & 7) * 64 + (blockIdx.x >> 3);
  const int b   = wid >> 4;
  const int ig  = wid & 15;

  if (tid < 64) maskL[tid] = em[b * 64 + tid];

  char* HhiB = LDSbuf;
  char* HloB = LDSbuf + 32768;

  // ---- resident B fragments: dblocks 2w, 2w+1 (static indices only) ----
  bfrag8 rbh0[8], rbl0[8], rbh1[8], rbl1[8];
  #pragma unroll
  for (int ks = 0; ks < 8; ++ks) {
    rbh0[ks] = *(const bfrag8*)&WfHi[((ks * 9 + 2 * w    ) * 64 + l) * 8];
    rbl0[ks] = *(const bfrag8*)&WfLo[((ks * 9 + 2 * w    ) * 64 + l) * 8];
    rbh1[ks] = *(const bfrag8*)&WfHi[((ks * 9 + 2 * w + 1) * 64 + l) * 8];
    rbl1[ks] = *(const bfrag8*)&WfLo[((ks * 9 + 2 * w + 1) * 64 + l) * 8];
  }

  const int laneJ = l & 15;
  const int laneK = l >> 4;
  const int addrA = laneJ * 512 + laneK * 16;
  const int swzA  = (laneJ & 7) << 4;

  #pragma unroll 1
  for (int ii = 0; ii < 4; ++ii) {
    const int rowi = b * 64 + ig * 4 + ii;
    const float emi = em[rowi];

    // ---- phase 1: build H[64][256] hi/lo.  thread: j = w*16+jsub*4+jj,
    //      k = kb*64 + laneJ*4 (+e) ----
    {
      const int jsub = laneK;               // 0..3
      const float pxi = positions[rowi * 4 + 0];
      const float pyi = positions[rowi * 4 + 1];
      float grx[4], gry[4], gdn[4], gdc[4];
      #pragma unroll
      for (int jj = 0; jj < 4; ++jj) {
        const int rowj = b * 64 + w * 16 + jsub * 4 + jj;
        const float rx = pxi - positions[rowj * 4 + 0];
        const float ry = pyi - positions[rowj * 4 + 1];
        const float d2 = rx * rx + ry * ry;
        const float dist = (d2 == 0.f) ? 0.f : sqrtf(d2);
        const float dn = dist * (1.0f / 50.0f);
        grx[jj] = rx; gry[jj] = ry; gdn[jj] = dn; gdc[jj] = fminf(dn, 1.f);
      }
      #pragma unroll 1
      for (int kb = 0; kb < 4; ++kb) {
        const int k = kb * 64 + laneJ * 4;
        const fvec4 a4 = *(const fvec4*)&Abuf[rowi * 256 + k];
        const fvec4 g0 = *(const fvec4*)&W1[512 * 256 + k];
        const fvec4 g1 = *(const fvec4*)&W1[513 * 256 + k];
        const fvec4 g2 = *(const fvec4*)&W1[514 * 256 + k];
        const fvec4 g3 = *(const fvec4*)&W1[515 * 256 + k];
        #pragma unroll
        for (int jj = 0; jj < 4; ++jj) {
          const int j = w * 16 + jsub * 4 + jj;
          const fvec4 c4 = *(const fvec4*)&Cbuf[(b * 64 + j) * 256 + k];
          spack4 hi, lo;
          #pragma unroll
          for (int e = 0; e < 4; ++e) {
            float h = a4[e] + c4[e] + grx[jj] * g0[e] + gry[jj] * g1[e]
                    + gdn[jj] * g2[e] + gdc[jj] * g3[e];
            h = fmaxf(h, 0.f);
            const short hb = f2bf(h);
            hi[e] = hb;
            lo[e] = f2bf(h - bf2f(hb));
          }
          const int byte = (j * 512 + k * 2) ^ ((j & 7) << 4);
          *(spack4*)(HhiB + byte) = hi;
          *(spack4*)(HloB + byte) = lo;
        }
      }
    }
    __syncthreads();

    // ---- phase 2: MFMA.  wave w: resident db {2w,2w+1} for all 4 jb;
    //      db8 streamed, jb==w only (balanced) ----
    fvec4 acc0[4], acc1[4], acc8;
    acc0[0] = 0.f; acc0[1] = 0.f; acc0[2] = 0.f; acc0[3] = 0.f;
    acc1[0] = 0.f; acc1[1] = 0.f; acc1[2] = 0.f; acc1[3] = 0.f;
    acc8 = 0.f;

    #pragma unroll
    for (int ks = 0; ks < 8; ++ks) {
      const bfrag8 bh8 = *(const bfrag8*)&WfHi[((ks * 9 + 8) * 64 + l) * 8];
      const bfrag8 bl8 = *(const bfrag8*)&WfLo[((ks * 9 + 8) * 64 + l) * 8];
      #pragma unroll
      for (int jb = 0; jb < 4; ++jb) {
        const int base = addrA + jb * 8192 + ks * 64;
        const bfrag8 ah = *(const bfrag8*)(HhiB + (base ^ swzA));
        const bfrag8 al = *(const bfrag8*)(HloB + (base ^ swzA));
        acc0[jb] = __builtin_amdgcn_mfma_f32_16x16x32_bf16(ah, rbh0[ks], acc0[jb], 0, 0, 0);
        acc0[jb] = __builtin_amdgcn_mfma_f32_16x16x32_bf16(ah, rbl0[ks], acc0[jb], 0, 0, 0);
        acc0[jb] = __builtin_amdgcn_mfma_f32_16x16x32_bf16(al, rbh0[ks], acc0[jb], 0, 0, 0);
        acc1[jb] = __builtin_amdgcn_mfma_f32_16x16x32_bf16(ah, rbh1[ks], acc1[jb], 0, 0, 0);
        acc1[jb] = __builtin_amdgcn_mfma_f32_16x16x32_bf16(ah, rbl1[ks], acc1[jb], 0, 0, 0);
        acc1[jb] = __builtin_amdgcn_mfma_f32_16x16x32_bf16(al, rbh1[ks], acc1[jb], 0, 0, 0);
        if (jb == w) {
          acc8 = __builtin_amdgcn_mfma_f32_16x16x32_bf16(ah, bh8, acc8, 0, 0, 0);
          acc8 = __builtin_amdgcn_mfma_f32_16x16x32_bf16(ah, bl8, acc8, 0, 0, 0);
          acc8 = __builtin_amdgcn_mfma_f32_16x16x32_bf16(al, bh8, acc8, 0, 0, 0);
        }
      }
    }
    __syncthreads();   // all H reads done; LDS front becomes FS[64][148]

    // ---- phase 3: bias+mask -> FS ----
    float* FS = (float*)LDSbuf;
    {
      const int d0 = 2 * w * 16 + laneJ;
      const int d1 = d0 + 16;
      const float bv0 = b2e[d0];
      const float bv1 = b2e[d1];
      #pragma unroll
      for (int jb = 0; jb < 4; ++jb) {
        #pragma unroll
        for (int r = 0; r < 4; ++r) {
          const int j = jb * 16 + laneK * 4 + r;
          const float m = emi * maskL[j];
          FS[j * 148 + d0] = (acc0[jb][r] + bv0) * m;
          FS[j * 148 + d1] = (acc1[jb][r] + bv1) * m;
        }
      }
      const int d8 = 128 + laneJ;
      const float bv8 = b2e[d8];
      #pragma unroll
      for (int r = 0; r < 4; ++r) {
        const int j = w * 16 + laneK * 4 + r;
        FS[j * 148 + d8] = (acc8[r] + bv8) * (emi * maskL[j]);
      }
    }
    __syncthreads();

    // ---- vectorized stores ----
    {
      const int j  = tid >> 2;           // 0..63
      const int dc = (tid & 3) * 32;     // 0,32,64,96
      const size_t orow = ((size_t)rowi * 64 + j) * 128;
      #pragma unroll
      for (int q = 0; q < 8; ++q) {
        const fvec4 v = *(const fvec4*)&FS[j * 148 + dc + q * 4];
        *(fvec4*)&out[orow + dc + q * 4] = v;
      }
    }
    {
      const int jq = tid >> 3;           // 0..31
      const int q8 = tid & 7;
      #pragma unroll
      for (int r = 0; r < 2; ++r) {
        const int j = r * 32 + jq;
        out[(size_t)ITY_OFF + ((size_t)rowi * 64 + j) * 8 + q8] =
            FS[j * 148 + 128 + q8] + bt[q8];
      }
      if (tid < 64) {
        const float z = FS[tid * 148 + 136] + bc[0];
        out[(size_t)CAU_OFF + (size_t)rowi * 64 + tid] =
            (emi * maskL[tid]) / (1.f + expf(-z));
      }
    }
    __syncthreads();   // FS fully consumed before next i's H overwrites
  }
}

// ---------------------------------------------------------------------------
extern "C" void kernel_launch(void* const* d_in, const int* in_sizes, int n_in,
                              void* d_out, int out_size, void* d_ws, size_t ws_size,
                              hipStream_t stream) {
  const float* slots     = (const float*)d_in[0];
  const float* positions = (const float*)d_in[1];
  const float* em        = (const float*)d_in[2];
  const float* W1        = (const float*)d_in[3];
  const float* b1        = (const float*)d_in[4];
  const float* W2        = (const float*)d_in[5];
  const float* b2        = (const float*)d_in[6];
  const float* Wt        = (const float*)d_in[7];
  const float* bt        = (const float*)d_in[8];
  const float* Wc        = (const float*)d_in[9];
  const float* bc        = (const float*)d_in[10];
  float* out = (float*)d_out;

  float* Abuf = (float*)d_ws;                   // [2048][256]
  float* Cbuf = Abuf + 524288;                  // [2048][256]
  float* b2e  = Cbuf + 524288;                  // [144] pad 256
  float* Wtx  = b2e + 256;                      // [256][16]
  short* WfHi = (short*)(Wtx + 4096);           // [72*64*8]
  short* WfLo = WfHi + 36864;

  prep_wtx<<<9,   256, 0, stream>>>(W2, b2, Wt, Wc, Wtx, b2e);
  prep_w  <<<18,  256, 0, stream>>>(W2, Wtx, WfHi, WfLo);
  prep_ac <<<512, 512, 0, stream>>>(slots, W1, b1, Abuf, Cbuf);
  main_kernel<<<512, 256, 0, stream>>>(positions, em, W1, Abuf, Cbuf,
                                       b2e, WfHi, WfLo, bt, bc, out);
}